// Round 9
// baseline (10505.872 us; speedup 1.0000x reference)
//
#include <hip/hip_runtime.h>
#include <stdint.h>

// ---------------------------------------------------------------------------
// R16 = R15 (9.95ms, PASS) with a LEADERLESS barrier.
//   Coherence model established by R11..R15 on MI355X:
//     - agent-scope RMWs execute at the fabric coherence point (cross-XCD
//       coherent; this is why counter barriers work at all).
//     - system-scope (SC0|SC1) stores/loads bypass L1+L2 and are performed
//       at that same coherence point (R14: h store->load correctness;
//       R15: go word store->load, 865 phases).
//     - plain loads are L2-cached -> need acquire-inv after the barrier.
//     - agent-scope loads/stores can be served by the LOCAL XCD L2 (R12
//       failure) -> never use them for cross-XCD data.
//   Therefore: pollers can observe the arrival counters DIRECTLY with
//   system-scope loads -> drop the leader + go-word indirection (R15's extra
//   2-3us/phase of hand-off hops). Release chain is now:
//     h system-stores acked -> vmcnt(0) drain (__syncthreads) -> arrival
//     agent-RMW (fire-and-forget) -> every block's own system-load poll sees
//     all 4 sub-counters -> acquire-inv -> plain b128 h loads refill via L2.
//   Everything else byte-identical to R15: system-scope packed h stores,
//   plain cached h reads, LDS-resident frag weights, 2 supergroups x 64
//   roles, 128 blk x 512 thr, Wy rank-1 y-feedback, emitY, abort guard.
// ---------------------------------------------------------------------------

typedef __attribute__((ext_vector_type(8))) short bfx8;   // 8 bf16 (4 VGPRs)
typedef __attribute__((ext_vector_type(4))) float fx4;

#define NBLK 128
#define NTHR 512
#define BH   (256*512)

__device__ __forceinline__ unsigned short f2bf(float f){
  unsigned u = __float_as_uint(f);
  u += 0x7FFFu + ((u >> 16) & 1u);          // RNE
  return (unsigned short)(u >> 16);
}
__device__ __forceinline__ float bf2f(unsigned short b){
  return __uint_as_float(((unsigned)b) << 16);
}
__device__ __forceinline__ float sigm(float x){ return 1.0f/(1.0f + __expf(-x)); }
__device__ __forceinline__ float tanhf_(float x){
  x = fminf(12.0f, fmaxf(-12.0f, x));
  float e = __expf(2.0f*x);
  return (e - 1.0f)/(e + 1.0f);
}

// 64-block supergroup barrier, leaderless.
//   arrival: relaxed agent RMW (fire-and-forget, 16 per sub-counter line,
//            4 lines spread across MALL slices).
//   poll:    4 parallel SYSTEM-scope relaxed loads (read at the coherence
//            point where the RMWs execute; no RMW serialization storm).
//   exit:    acquire load -> buffer_inv so plain h loads refill fresh.
__device__ __forceinline__ bool groupbar(unsigned* cntg, int sub, unsigned gen,
                                         unsigned* abortf, volatile unsigned* s_abort){
  __syncthreads();
  if (threadIdx.x == 0){
    __hip_atomic_fetch_add(cntg + sub*32, 1u, __ATOMIC_RELAXED, __HIP_MEMORY_SCOPE_AGENT);
    const unsigned target = gen*16u;
    unsigned spins = 0;
    for (;;){
      unsigned v0 = __hip_atomic_load(cntg +  0, __ATOMIC_RELAXED, __HIP_MEMORY_SCOPE_SYSTEM);
      unsigned v1 = __hip_atomic_load(cntg + 32, __ATOMIC_RELAXED, __HIP_MEMORY_SCOPE_SYSTEM);
      unsigned v2 = __hip_atomic_load(cntg + 64, __ATOMIC_RELAXED, __HIP_MEMORY_SCOPE_SYSTEM);
      unsigned v3 = __hip_atomic_load(cntg + 96, __ATOMIC_RELAXED, __HIP_MEMORY_SCOPE_SYSTEM);
      if (v0 >= target && v1 >= target && v2 >= target && v3 >= target) break;
      if (((++spins) & 1023u) == 0u){
        if (__hip_atomic_load(abortf, __ATOMIC_RELAXED, __HIP_MEMORY_SCOPE_AGENT) != 0u){
          *s_abort = 1u; break;
        }
        if (spins > (1u << 20)){
          __hip_atomic_store(abortf, 1u, __ATOMIC_RELAXED, __HIP_MEMORY_SCOPE_AGENT);
          *s_abort = 1u; break;
        }
      }
      __builtin_amdgcn_s_sleep(1);
    }
    (void)__hip_atomic_load(cntg, __ATOMIC_ACQUIRE, __HIP_MEMORY_SCOPE_AGENT);  // buffer_inv
  }
  __syncthreads();
  return *s_abort != 0u;
}

// K=512 accumulate: A rows from global h via PLAIN b128 loads (L2-cached,
// shared across the XCD's blocks; fresh after the barrier's buffer_inv);
// B = 4 gate-slices from LDS fragment layout ([gate][kc][lane][8]).
__device__ __forceinline__ void accK512_lds(fx4* acc, const uint16_t* aq,
                                            const uint16_t* wl, int lane8){
  #pragma unroll
  for (int kc = 0; kc < 16; ++kc){
    bfx8 af = *(const bfx8*)(aq + kc*32);
    acc[0] = __builtin_amdgcn_mfma_f32_16x16x32_bf16(af, *(const bfx8*)(wl +         kc*512 + lane8), acc[0], 0, 0, 0);
    acc[1] = __builtin_amdgcn_mfma_f32_16x16x32_bf16(af, *(const bfx8*)(wl +  8192 + kc*512 + lane8), acc[1], 0, 0, 0);
    acc[2] = __builtin_amdgcn_mfma_f32_16x16x32_bf16(af, *(const bfx8*)(wl + 16384 + kc*512 + lane8), acc[2], 0, 0, 0);
    acc[3] = __builtin_amdgcn_mfma_f32_16x16x32_bf16(af, *(const bfx8*)(wl + 24576 + kc*512 + lane8), acc[3], 0, 0, 0);
  }
}

// LSTM pointwise; h store = packed 2-col SYSTEM-scope atomic dword (write-
// through to the coherence point; acked before vmcnt(0) drain).
__device__ __forceinline__ void pointwise(fx4* acc, fx4& creg, int bq, int u,
                                          int col, uint16_t* hout){
  #pragma unroll
  for (int r = 0; r < 4; ++r){
    float iv = sigm(acc[0][r]);
    float fv = sigm(acc[1][r]);
    float gv = tanhf_(acc[2][r]);
    float ov = sigm(acc[3][r]);
    float cn = fv * creg[r] + iv * gv;
    creg[r] = cn;
    unsigned hb = (unsigned)f2bf(ov * tanhf_(cn));
    unsigned nb = __shfl_xor(hb, 1);
    if ((col & 1) == 0){
      __hip_atomic_store((unsigned*)(hout + (size_t)(bq + r)*512 + u), hb | (nb << 16),
                         __ATOMIC_RELAXED, __HIP_MEMORY_SCOPE_SYSTEM);
    }
  }
}

__global__ void __launch_bounds__(NTHR, 2)
seq2seq_main(const uint16_t* __restrict__ Whh0e, const uint16_t* __restrict__ Wih1e,
             const uint16_t* __restrict__ Whh1e, const uint16_t* __restrict__ Whh0d,
             const uint16_t* __restrict__ Wih1d, const uint16_t* __restrict__ Whh1d,
             const uint16_t* __restrict__ Wy,
             const float* __restrict__ E0e, const float* __restrict__ E0d,
             const float* __restrict__ b1e, const float* __restrict__ b1d,
             const float* __restrict__ wcol0,
             uint16_t* h0buf, uint16_t* h1buf,
             const float* __restrict__ xh, const float* __restrict__ xf,
             const float* __restrict__ y0v,
             const float* __restrict__ encWih0, const float* __restrict__ decWih0,
             const float* __restrict__ projW, const float* __restrict__ projB,
             float* out, unsigned* cntBase)
{
  __shared__ uint4 smem4[8192];                 // 128 KiB static LDS
  __shared__ unsigned s_abort;
  uint16_t* smem = (uint16_t*)smem4;

  const int tid  = threadIdx.x;
  const int lane = tid & 63;
  const int wvi  = tid >> 6;                    // wave in block, 0..7
  const int gh   = wvi >> 2;                    // batch-half within supergroup
  const int wv4  = wvi & 3;                     // M-tile index within half
  const int sg   = blockIdx.x >> 6;             // supergroup (128 batch rows)
  const int k    = blockIdx.x & 63;             // role: 0..31 L0, 32..63 L1
  const bool isL0 = (k < 32);
  const int role = isL0 ? k : k - 32;           // u-slice index, 0..31
  const int col  = lane & 15;
  const int quad = lane >> 4;
  const int g    = (sg << 1) + gh;              // logical 64-row group, 0..3
  const int rowbase = (g << 6) + (wv4 << 4);    // wave's 16-row M-tile base
  const int bq   = rowbase + (quad << 2);
  const int u    = (role << 4) + col;
  const int lane8 = lane << 3;
  unsigned* cntg = cntBase + (size_t)sg * 128;  // 4 counters x 128B / supergroup
  unsigned* abortf = cntBase + 256;             // abort flag (own line, zeroed)
  const int sub  = k >> 4;
  unsigned gen = 0;
  fx4 creg = {0.f, 0.f, 0.f, 0.f};              // c0 (L0) or c1 (L1)
  const float projB_val = projB[0];

  if (tid == 0) s_abort = 0u;

  uint16_t *h0A = h0buf, *h0B = h0buf + BH;
  uint16_t *h1A = h1buf, *h1B = h1buf + BH;

  // ---- stage encoder weight slices into LDS ----
  if (isL0){
    const uint4* s0 = (const uint4*)(Whh0e + (size_t)role*32768);
    for (int i = tid; i < 4096; i += NTHR) smem4[i] = s0[i];
  } else {
    const uint4* s0 = (const uint4*)(Wih1e + (size_t)role*32768);
    const uint4* s1 = (const uint4*)(Whh1e + (size_t)role*32768);
    for (int i = tid; i < 4096; i += NTHR){ smem4[i] = s0[i]; smem4[4096+i] = s1[i]; }
  }

  // ---- hoist per-lane constants into registers ----
  float e0r[4][4], xw[4][8], wc[4], b1r[4], pw8[8];
  if (isL0){
    #pragma unroll
    for (int gg = 0; gg < 4; ++gg){
      #pragma unroll
      for (int r = 0; r < 4; ++r)
        e0r[gg][r] = E0e[(size_t)(bq + r)*2048 + (gg << 9) + u];
      #pragma unroll
      for (int kk = 0; kk < 8; ++kk)
        xw[gg][kk] = encWih0[(size_t)((gg << 9) + u)*24 + kk];
    }
  } else {
    #pragma unroll
    for (int gg = 0; gg < 4; ++gg) b1r[gg] = b1e[(gg << 9) + u];
    if (k < 36){                                // emitY blocks k=32..35
      #pragma unroll
      for (int kk = 0; kk < 8; ++kk) pw8[kk] = projW[lane8 + kk];
    }
  }
  __syncthreads();

  auto encCompute = [&](int tt, const uint16_t* h0c, uint16_t* h0n){
    fx4 acc[4];
    #pragma unroll
    for (int gg = 0; gg < 4; ++gg)
      #pragma unroll
      for (int r = 0; r < 4; ++r) acc[gg][r] = e0r[gg][r];
    float xv[4][8];
    #pragma unroll
    for (int r = 0; r < 4; ++r){
      const float* xr = xh + ((size_t)(bq + r)*288 + tt)*8;
      #pragma unroll
      for (int kk = 0; kk < 8; ++kk) xv[r][kk] = xr[kk];
    }
    accK512_lds(acc, h0c + (size_t)(rowbase + col)*512 + (quad << 3), smem, lane8);
    #pragma unroll
    for (int gg = 0; gg < 4; ++gg)
      #pragma unroll
      for (int kk = 0; kk < 8; ++kk){
        float w = xw[gg][kk];
        #pragma unroll
        for (int r = 0; r < 4; ++r) acc[gg][r] += w * xv[r][kk];
      }
    pointwise(acc, creg, bq, u, col, h0n);
  };

  // emitY: blocks k=32..35; per half, wave wv4 covers 4 rows. Plain loads
  // (fresh after barrier inv); single-writer out stores.
  auto emitY = [&](const uint16_t* h1cur, int tt){
    int rb = (g << 6) + ((k - 32) << 4) + (wv4 << 2);
    #pragma unroll 1
    for (int j = 0; j < 4; ++j){
      int b = rb + j;
      const uint16_t* hr = h1cur + (size_t)b*512 + lane8;
      float part = 0.f;
      #pragma unroll
      for (int kk = 0; kk < 8; ++kk) part += bf2f(hr[kk]) * pw8[kk];
      #pragma unroll
      for (int off = 32; off > 0; off >>= 1) part += __shfl_down(part, off);
      if (lane == 0) out[(size_t)b*288 + tt] = part + projB_val;
    }
  };

  // ---- prologue: enc L0 t=0 (h_{-1}=0 via memset) ----
  if (isL0) encCompute(0, h0A, h0B);
  if (groupbar(cntg, sub, ++gen, abortf, &s_abort)) return;
  { uint16_t* t_ = h0A; h0A = h0B; h0B = t_; }   // h0A = h0_0

  // ---- encoder: 1 barrier/step; L1_t || L0_{t+1} ----
  #pragma unroll 1
  for (int t = 0; t < 288; ++t){
    if (isL0){
      if (t < 287) encCompute(t + 1, h0A, h0B);
    } else {
      fx4 acc[4];
      #pragma unroll
      for (int gg = 0; gg < 4; ++gg)
        #pragma unroll
        for (int r = 0; r < 4; ++r) acc[gg][r] = b1r[gg];
      accK512_lds(acc, h0A + (size_t)(rowbase + col)*512 + (quad << 3), smem, lane8);          // Wih1e
      accK512_lds(acc, h1A + (size_t)(rowbase + col)*512 + (quad << 3), smem + 32768, lane8);  // Whh1e
      pointwise(acc, creg, bq, u, col, h1B);
    }
    if (groupbar(cntg, sub, ++gen, abortf, &s_abort)) return;
    { uint16_t* t_ = h1A; h1A = h1B; h1B = t_; }
    if (t < 287){ uint16_t* t_ = h0A; h0A = h0B; h0B = t_; }
  }
  // h0A = h0_287, h1A = h1_287; c continues into decoder.

  // ---- restage decoder weights + regs (block-local) ----
  if (isL0){
    const uint4* s0 = (const uint4*)(Whh0d + (size_t)role*32768);
    const uint4* s1 = (const uint4*)(Wy    + (size_t)role*32768);
    for (int i = tid; i < 4096; i += NTHR){ smem4[i] = s0[i]; smem4[4096+i] = s1[i]; }
    #pragma unroll
    for (int gg = 0; gg < 4; ++gg){
      #pragma unroll
      for (int r = 0; r < 4; ++r)
        e0r[gg][r] = E0d[(size_t)(bq + r)*2048 + (gg << 9) + u];
      #pragma unroll
      for (int kk = 0; kk < 6; ++kk)
        xw[gg][kk] = decWih0[(size_t)((gg << 9) + u)*23 + 1 + kk];
      wc[gg] = wcol0[(gg << 9) + u];
    }
  } else {
    const uint4* s0 = (const uint4*)(Wih1d + (size_t)role*32768);
    const uint4* s1 = (const uint4*)(Whh1d + (size_t)role*32768);
    for (int i = tid; i < 4096; i += NTHR){ smem4[i] = s0[i]; smem4[4096+i] = s1[i]; }
    #pragma unroll
    for (int gg = 0; gg < 4; ++gg) b1r[gg] = b1d[(gg << 9) + u];
  }
  __syncthreads();

  auto decCompute = [&](int tt, const uint16_t* h0c, const uint16_t* h1c,
                        uint16_t* h0n){
    fx4 acc[4];
    #pragma unroll
    for (int gg = 0; gg < 4; ++gg)
      #pragma unroll
      for (int r = 0; r < 4; ++r) acc[gg][r] = e0r[gg][r];
    accK512_lds(acc, h0c + (size_t)(rowbase + col)*512 + (quad << 3), smem, lane8);           // Whh0d
    if (tt > 0)
      accK512_lds(acc, h1c + (size_t)(rowbase + col)*512 + (quad << 3), smem + 32768, lane8); // Wy
    float s[4];
    #pragma unroll
    for (int r = 0; r < 4; ++r) s[r] = (tt == 0) ? y0v[bq + r] : projB_val;
    float xv[4][6];
    #pragma unroll
    for (int r = 0; r < 4; ++r){
      const float* xr = xf + ((size_t)(bq + r)*288 + tt)*6;
      #pragma unroll
      for (int kk = 0; kk < 6; ++kk) xv[r][kk] = xr[kk];
    }
    #pragma unroll
    for (int gg = 0; gg < 4; ++gg){
      #pragma unroll
      for (int r = 0; r < 4; ++r) acc[gg][r] += wc[gg] * s[r];
      #pragma unroll
      for (int kk = 0; kk < 6; ++kk){
        float w = xw[gg][kk];
        #pragma unroll
        for (int r = 0; r < 4; ++r) acc[gg][r] += w * xv[r][kk];
      }
    }
    pointwise(acc, creg, bq, u, col, h0n);
  };

  // ---- decoder: 2 barriers/step (R7 structure) ----
  #pragma unroll 1
  for (int t = 0; t < 288; ++t){
    if (isL0){
      decCompute(t, h0A, h1A, h0B);
    } else if (k < 36 && t > 0){
      emitY(h1A, t - 1);
    }
    if (groupbar(cntg, sub, ++gen, abortf, &s_abort)) return;
    if (!isL0){
      fx4 acc[4];
      #pragma unroll
      for (int gg = 0; gg < 4; ++gg)
        #pragma unroll
        for (int r = 0; r < 4; ++r) acc[gg][r] = b1r[gg];
      accK512_lds(acc, h1A + (size_t)(rowbase + col)*512 + (quad << 3), smem + 32768, lane8); // Whh1d
      accK512_lds(acc, h0B + (size_t)(rowbase + col)*512 + (quad << 3), smem, lane8);         // Wih1d
      pointwise(acc, creg, bq, u, col, h1B);
    }
    if (groupbar(cntg, sub, ++gen, abortf, &s_abort)) return;
    { uint16_t* t_ = h0A; h0A = h0B; h0B = t_; }
    { uint16_t* t_ = h1A; h1A = h1B; h1B = t_; }
  }

  // final y_287 (h1A = h1_287, published by last barrier)
  if (!isL0 && k < 36) emitY(h1A, 287);
}

// ---------------- prep: frag-ordered bf16 weights (+Wy), emb+bias folds ----
#define PREP_S 1048576
#define PREP_TOTAL (7*PREP_S + 1048576 + 6144)

__global__ void __launch_bounds__(256)
prep_kernel(const float* __restrict__ encWih0, const float* __restrict__ encWhh0,
            const float* __restrict__ encWih1, const float* __restrict__ encWhh1,
            const float* __restrict__ decWih0, const float* __restrict__ decWhh0,
            const float* __restrict__ decWih1, const float* __restrict__ decWhh1,
            const float* __restrict__ encbih0, const float* __restrict__ encbhh0,
            const float* __restrict__ encbih1, const float* __restrict__ encbhh1,
            const float* __restrict__ decbih0, const float* __restrict__ decbhh0,
            const float* __restrict__ decbih1, const float* __restrict__ decbhh1,
            const float* __restrict__ projW, const float* __restrict__ emb,
            const int* __restrict__ turb,
            uint16_t* Whh0e, uint16_t* Wih1e, uint16_t* Whh1e,
            uint16_t* Whh0d, uint16_t* Wih1d, uint16_t* Whh1d, uint16_t* Wyp,
            float* E0e, float* E0d, float* b1e, float* b1d, float* wcol0)
{
  int i = blockIdx.x*256 + threadIdx.x;
  if (i >= PREP_TOTAL) return;
  if (i < 7*PREP_S){
    // fragment reorder: dest = role*32768 + gate*8192 + kc*512 + lane*8 + j
    // value = W[gate*512 + role*16 + (lane&15)][kc*32 + (lane>>4)*8 + j]
    int w = i >> 20, r = i & (PREP_S - 1);
    int role = r >> 15;
    int rem  = r & 32767;
    int gate = rem >> 13;
    int kc   = (rem >> 9) & 15;
    int ln   = (rem >> 3) & 63;
    int j    = rem & 7;
    int c = ln & 15, q = ln >> 4;
    int row  = (gate << 9) + (role << 4) + c;
    int colk = (kc << 5) + (q << 3) + j;
    float v;
    if (w == 6){
      v = decWih0[(size_t)row*23] * projW[colk];     // Wy = wcol0 (x) projW
    } else {
      const float* src = (w==0)?encWhh0:(w==1)?encWih1:(w==2)?encWhh1:
                         (w==3)?decWhh0:(w==4)?decWih1:decWhh1;
      v = src[(size_t)row*512 + colk];
    }
    uint16_t* dst = (w==0)?Whh0e:(w==1)?Wih1e:(w==2)?Whh1e:
                    (w==3)?Whh0d:(w==4)?Wih1d:(w==5)?Whh1d:Wyp;
    dst[r] = f2bf(v);
  } else if (i < 7*PREP_S + 524288){
    int r = i - 7*PREP_S; int b = r >> 11, j = r & 2047;
    float s = encbih0[j] + encbhh0[j];
    const float* e = emb + (size_t)turb[b]*16;
    const float* wr = encWih0 + (size_t)j*24 + 8;
    #pragma unroll
    for (int m = 0; m < 16; ++m) s += e[m]*wr[m];
    E0e[r] = s;
  } else if (i < 7*PREP_S + 1048576){
    int r = i - 7*PREP_S - 524288; int b = r >> 11, j = r & 2047;
    float s = decbih0[j] + decbhh0[j];
    const float* e = emb + (size_t)turb[b]*16;
    const float* wr = decWih0 + (size_t)j*23 + 7;
    #pragma unroll
    for (int m = 0; m < 16; ++m) s += e[m]*wr[m];
    E0d[r] = s;
  } else {
    int r = i - 7*PREP_S - 1048576;
    if (r < 2048)      b1e[r] = encbih1[r] + encbhh1[r];
    else if (r < 4096){ int j = r - 2048; b1d[j] = decbih1[j] + decbhh1[j]; }
    else              { int j = r - 4096; wcol0[j] = decWih0[(size_t)j*23]; }
  }
}

// ---------------------------------------------------------------------------
extern "C" void kernel_launch(void* const* d_in, const int* in_sizes, int n_in,
                              void* d_out, int out_size, void* d_ws, size_t ws_size,
                              hipStream_t stream)
{
  const float* xh      = (const float*)d_in[0];
  const float* xf      = (const float*)d_in[1];
  const float* y0v     = (const float*)d_in[2];
  const int*   turb    = (const int*)d_in[3];
  const float* emb     = (const float*)d_in[5];
  const float* encWih0 = (const float*)d_in[6];
  const float* encWhh0 = (const float*)d_in[7];
  const float* encbih0 = (const float*)d_in[8];
  const float* encbhh0 = (const float*)d_in[9];
  const float* encWih1 = (const float*)d_in[10];
  const float* encWhh1 = (const float*)d_in[11];
  const float* encbih1 = (const float*)d_in[12];
  const float* encbhh1 = (const float*)d_in[13];
  const float* decWih0 = (const float*)d_in[14];
  const float* decWhh0 = (const float*)d_in[15];
  const float* decbih0 = (const float*)d_in[16];
  const float* decbhh0 = (const float*)d_in[17];
  const float* decWih1 = (const float*)d_in[18];
  const float* decWhh1 = (const float*)d_in[19];
  const float* decbih1 = (const float*)d_in[20];
  const float* decbhh1 = (const float*)d_in[21];
  const float* projW   = (const float*)d_in[22];
  const float* projB   = (const float*)d_in[23];
  float* out = (float*)d_out;

  char* ws = (char*)d_ws;
  constexpr size_t SZW = (size_t)2048*512*2;        // 2 MiB per matrix
  constexpr size_t OFF_Whh0e = 0;
  constexpr size_t OFF_Wih1e = SZW;
  constexpr size_t OFF_Whh1e = 2*SZW;
  constexpr size_t OFF_Whh0d = 3*SZW;
  constexpr size_t OFF_Wih1d = 4*SZW;
  constexpr size_t OFF_Whh1d = 5*SZW;
  constexpr size_t OFF_Wy    = 6*SZW;
  constexpr size_t OFF_E0e   = 7*SZW;
  constexpr size_t OFF_E0d   = OFF_E0e + 2097152;
  constexpr size_t OFF_b1e   = OFF_E0d + 2097152;
  constexpr size_t OFF_b1d   = OFF_b1e + 8192;
  constexpr size_t OFF_wcol0 = OFF_b1d + 8192;
  constexpr size_t OFF_h0    = OFF_wcol0 + 8192;
  constexpr size_t OFF_h1    = OFF_h0 + 524288;
  constexpr size_t OFF_cnt   = OFF_h1 + 524288;
  constexpr size_t ZERO_BYTES = 2*524288 + 2048;    // h0,h1 ping-pong + counters+abort

  uint16_t* Whh0e = (uint16_t*)(ws + OFF_Whh0e);
  uint16_t* Wih1e = (uint16_t*)(ws + OFF_Wih1e);
  uint16_t* Whh1e = (uint16_t*)(ws + OFF_Whh1e);
  uint16_t* Whh0d = (uint16_t*)(ws + OFF_Whh0d);
  uint16_t* Wih1d = (uint16_t*)(ws + OFF_Wih1d);
  uint16_t* Whh1d = (uint16_t*)(ws + OFF_Whh1d);
  uint16_t* Wyp   = (uint16_t*)(ws + OFF_Wy);
  float* E0e   = (float*)(ws + OFF_E0e);
  float* E0d   = (float*)(ws + OFF_E0d);
  float* b1e   = (float*)(ws + OFF_b1e);
  float* b1d   = (float*)(ws + OFF_b1d);
  float* wcol0 = (float*)(ws + OFF_wcol0);
  uint16_t* h0p = (uint16_t*)(ws + OFF_h0);
  uint16_t* h1p = (uint16_t*)(ws + OFF_h1);
  unsigned* cntp = (unsigned*)(ws + OFF_cnt);

  hipMemsetAsync(ws + OFF_h0, 0, ZERO_BYTES, stream);

  prep_kernel<<<dim3((PREP_TOTAL + 255)/256), dim3(256), 0, stream>>>(
      encWih0, encWhh0, encWih1, encWhh1, decWih0, decWhh0, decWih1, decWhh1,
      encbih0, encbhh0, encbih1, encbhh1, decbih0, decbhh0, decbih1, decbhh1,
      projW, emb, turb,
      Whh0e, Wih1e, Whh1e, Whh0d, Wih1d, Whh1d, Wyp,
      E0e, E0d, b1e, b1d, wcol0);

  // Plain launch (proven R11/R14/R15). 128 blocks on 256 CUs @ 1 block/CU ->
  // co-residency with 2x slack; barrier spin is abort-guarded.
  seq2seq_main<<<dim3(NBLK), dim3(NTHR), 0, stream>>>(
      Whh0e, Wih1e, Whh1e, Whh0d, Wih1d, Whh1d, Wyp,
      E0e, E0d, b1e, b1d, wcol0,
      h0p, h1p, xh, xf, y0v,
      encWih0, decWih0, projW, projB,
      out, cntp);
}

// Round 10
// 10433.527 us; speedup vs baseline: 1.0069x; 1.0069x over previous
//
#include <hip/hip_runtime.h>
#include <stdint.h>

// ---------------------------------------------------------------------------
// R17 = R15/R16 data path + DIRECTED producer->consumer synchronization.
//   R15 (9.95ms) / R16 (10.5ms) pay 2 full 64-block barriers per decoder step
//   (~10us sync/phase, compute ~1us). But each barrier is really a 32->32
//   handoff: L0 publishes h0, L1 consumes; L1 publishes h1, L0 consumes.
//   R17 splits the counters by role-set (lines 0,1 = L0 arrivals; 2,3 = L1)
//   and each block WAITS only on what its inputs need, ARRIVES only when it
//   publishes:
//     enc L0 step t: wait(L0>=16t, L1>=16(t-1)) -> h0_t -> arrive L0
//     enc L1 step t: wait(L0>=16(t+1), L1>=16t) -> h1_t -> arrive L1
//     dec L0 step t: wait(L0>=16(288+t), L1>=16(288+t)) -> h0_t -> arrive
//     dec L1 step t: wait(L0>=16(289+t), L1>=16(288+t)) -> emitY(t-1), h1_t
//   One wait+inv and one arrival per block per step (was 2 barriers); arrival
//   RMWs halve; idle-role gather latency eliminated. Overwrite safety is in
//   the wait inequalities (h_s -> buf[s&1]; all readers of the overwritten
//   buffer have provably arrived). h_{-1} = zeroed buf[1].
//   Data path unchanged (all HW-proven): system-scope packed h stores
//   (write-through, no wbl2 needed), plain b128 h reads + acquire-inv after
//   wait-detect (L2-shared refills), system-scope relaxed counter polls
//   (R16-proven), agent RMW arrivals, LDS-resident frag weights, Wy rank-1
//   y-feedback, emitY single-writer, abort-guarded waits.
// ---------------------------------------------------------------------------

typedef __attribute__((ext_vector_type(8))) short bfx8;   // 8 bf16 (4 VGPRs)
typedef __attribute__((ext_vector_type(4))) float fx4;

#define NBLK 128
#define NTHR 512
#define BH   (256*512)

__device__ __forceinline__ unsigned short f2bf(float f){
  unsigned u = __float_as_uint(f);
  u += 0x7FFFu + ((u >> 16) & 1u);          // RNE
  return (unsigned short)(u >> 16);
}
__device__ __forceinline__ float bf2f(unsigned short b){
  return __uint_as_float(((unsigned)b) << 16);
}
__device__ __forceinline__ float sigm(float x){ return 1.0f/(1.0f + __expf(-x)); }
__device__ __forceinline__ float tanhf_(float x){
  x = fminf(12.0f, fmaxf(-12.0f, x));
  float e = __expf(2.0f*x);
  return (e - 1.0f)/(e + 1.0f);
}

// Directed wait: block until L0-lines >= t01 and L1-lines >= t23, then
// acquire-inv (refresh L2 for plain h reads). Poll = system-scope relaxed
// loads (read at the coherence point where arrival RMWs execute; R16-proven).
__device__ __forceinline__ bool waitCnt(unsigned* cntg, unsigned t01, unsigned t23,
                                        unsigned* abortf, volatile unsigned* s_abort){
  if (threadIdx.x == 0){
    unsigned spins = 0;
    for (;;){
      unsigned v0 = __hip_atomic_load(cntg +  0, __ATOMIC_RELAXED, __HIP_MEMORY_SCOPE_SYSTEM);
      unsigned v1 = __hip_atomic_load(cntg + 32, __ATOMIC_RELAXED, __HIP_MEMORY_SCOPE_SYSTEM);
      unsigned v2 = __hip_atomic_load(cntg + 64, __ATOMIC_RELAXED, __HIP_MEMORY_SCOPE_SYSTEM);
      unsigned v3 = __hip_atomic_load(cntg + 96, __ATOMIC_RELAXED, __HIP_MEMORY_SCOPE_SYSTEM);
      if (v0 >= t01 && v1 >= t01 && v2 >= t23 && v3 >= t23) break;
      if (((++spins) & 1023u) == 0u){
        if (__hip_atomic_load(abortf, __ATOMIC_RELAXED, __HIP_MEMORY_SCOPE_AGENT) != 0u){
          *s_abort = 1u; break;
        }
        if (spins > (1u << 20)){
          __hip_atomic_store(abortf, 1u, __ATOMIC_RELAXED, __HIP_MEMORY_SCOPE_AGENT);
          *s_abort = 1u; break;
        }
      }
      __builtin_amdgcn_s_sleep(1);
    }
    (void)__hip_atomic_load(cntg, __ATOMIC_ACQUIRE, __HIP_MEMORY_SCOPE_AGENT);  // buffer_inv
  }
  __syncthreads();
  return *s_abort != 0u;
}

// Publish: __syncthreads drains every wave's system h-stores (vmcnt(0) before
// s_barrier), then one agent RMW on this block's sub-counter line.
__device__ __forceinline__ void arriveCnt(unsigned* cntline){
  __syncthreads();
  if (threadIdx.x == 0)
    __hip_atomic_fetch_add(cntline, 1u, __ATOMIC_RELAXED, __HIP_MEMORY_SCOPE_AGENT);
}

// K=512 accumulate: A rows from global h via PLAIN b128 loads (L2-cached,
// fresh after waitCnt's inv); B = 4 gate-slices from LDS fragment layout.
__device__ __forceinline__ void accK512_lds(fx4* acc, const uint16_t* aq,
                                            const uint16_t* wl, int lane8){
  #pragma unroll
  for (int kc = 0; kc < 16; ++kc){
    bfx8 af = *(const bfx8*)(aq + kc*32);
    acc[0] = __builtin_amdgcn_mfma_f32_16x16x32_bf16(af, *(const bfx8*)(wl +         kc*512 + lane8), acc[0], 0, 0, 0);
    acc[1] = __builtin_amdgcn_mfma_f32_16x16x32_bf16(af, *(const bfx8*)(wl +  8192 + kc*512 + lane8), acc[1], 0, 0, 0);
    acc[2] = __builtin_amdgcn_mfma_f32_16x16x32_bf16(af, *(const bfx8*)(wl + 16384 + kc*512 + lane8), acc[2], 0, 0, 0);
    acc[3] = __builtin_amdgcn_mfma_f32_16x16x32_bf16(af, *(const bfx8*)(wl + 24576 + kc*512 + lane8), acc[3], 0, 0, 0);
  }
}

// LSTM pointwise; h store = packed 2-col SYSTEM-scope atomic dword (write-
// through to the coherence point; acked before the arrival's vmcnt drain).
__device__ __forceinline__ void pointwise(fx4* acc, fx4& creg, int bq, int u,
                                          int col, uint16_t* hout){
  #pragma unroll
  for (int r = 0; r < 4; ++r){
    float iv = sigm(acc[0][r]);
    float fv = sigm(acc[1][r]);
    float gv = tanhf_(acc[2][r]);
    float ov = sigm(acc[3][r]);
    float cn = fv * creg[r] + iv * gv;
    creg[r] = cn;
    unsigned hb = (unsigned)f2bf(ov * tanhf_(cn));
    unsigned nb = __shfl_xor(hb, 1);
    if ((col & 1) == 0){
      __hip_atomic_store((unsigned*)(hout + (size_t)(bq + r)*512 + u), hb | (nb << 16),
                         __ATOMIC_RELAXED, __HIP_MEMORY_SCOPE_SYSTEM);
    }
  }
}

__global__ void __launch_bounds__(NTHR, 2)
seq2seq_main(const uint16_t* __restrict__ Whh0e, const uint16_t* __restrict__ Wih1e,
             const uint16_t* __restrict__ Whh1e, const uint16_t* __restrict__ Whh0d,
             const uint16_t* __restrict__ Wih1d, const uint16_t* __restrict__ Whh1d,
             const uint16_t* __restrict__ Wy,
             const float* __restrict__ E0e, const float* __restrict__ E0d,
             const float* __restrict__ b1e, const float* __restrict__ b1d,
             const float* __restrict__ wcol0,
             uint16_t* h0buf, uint16_t* h1buf,
             const float* __restrict__ xh, const float* __restrict__ xf,
             const float* __restrict__ y0v,
             const float* __restrict__ encWih0, const float* __restrict__ decWih0,
             const float* __restrict__ projW, const float* __restrict__ projB,
             float* out, unsigned* cntBase)
{
  __shared__ uint4 smem4[8192];                 // 128 KiB static LDS
  __shared__ unsigned s_abort;
  uint16_t* smem = (uint16_t*)smem4;

  const int tid  = threadIdx.x;
  const int lane = tid & 63;
  const int wvi  = tid >> 6;                    // wave in block, 0..7
  const int gh   = wvi >> 2;                    // batch-half within supergroup
  const int wv4  = wvi & 3;                     // M-tile index within half
  const int sg   = blockIdx.x >> 6;             // supergroup (128 batch rows)
  const int k    = blockIdx.x & 63;             // role: 0..31 L0, 32..63 L1
  const bool isL0 = (k < 32);
  const int role = isL0 ? k : k - 32;           // u-slice index, 0..31
  const int col  = lane & 15;
  const int quad = lane >> 4;
  const int g    = (sg << 1) + gh;              // logical 64-row group, 0..3
  const int rowbase = (g << 6) + (wv4 << 4);    // wave's 16-row M-tile base
  const int bq   = rowbase + (quad << 2);
  const int u    = (role << 4) + col;
  const int lane8 = lane << 3;
  unsigned* cntg = cntBase + (size_t)sg * 128;  // 4 counters x 128B / supergroup
  unsigned* abortf = cntBase + 256;             // abort flag (own line, zeroed)
  unsigned* myline = cntg + (k >> 4)*32;        // L0 -> lines 0,1; L1 -> 2,3
  unsigned gen = 0;
  fx4 creg = {0.f, 0.f, 0.f, 0.f};              // c0 (L0) or c1 (L1)
  const float projB_val = projB[0];
  const int hoff = (size_t)0 + (rowbase + col)*512 + (quad << 3);

  if (tid == 0) s_abort = 0u;

  // h_s lives in buf[s&1]; h_{-1} = zeroed buf[1].
  uint16_t* h0b[2] = { h0buf, h0buf + BH };
  uint16_t* h1b[2] = { h1buf, h1buf + BH };

  // ---- stage encoder weight slices into LDS ----
  if (isL0){
    const uint4* s0 = (const uint4*)(Whh0e + (size_t)role*32768);
    for (int i = tid; i < 4096; i += NTHR) smem4[i] = s0[i];
  } else {
    const uint4* s0 = (const uint4*)(Wih1e + (size_t)role*32768);
    const uint4* s1 = (const uint4*)(Whh1e + (size_t)role*32768);
    for (int i = tid; i < 4096; i += NTHR){ smem4[i] = s0[i]; smem4[4096+i] = s1[i]; }
  }

  // ---- hoist per-lane constants into registers ----
  float e0r[4][4], xw[4][8], wc[4], b1r[4], pw8[8];
  if (isL0){
    #pragma unroll
    for (int gg = 0; gg < 4; ++gg){
      #pragma unroll
      for (int r = 0; r < 4; ++r)
        e0r[gg][r] = E0e[(size_t)(bq + r)*2048 + (gg << 9) + u];
      #pragma unroll
      for (int kk = 0; kk < 8; ++kk)
        xw[gg][kk] = encWih0[(size_t)((gg << 9) + u)*24 + kk];
    }
  } else {
    #pragma unroll
    for (int gg = 0; gg < 4; ++gg) b1r[gg] = b1e[(gg << 9) + u];
    if (k < 36){                                // emitY blocks k=32..35
      #pragma unroll
      for (int kk = 0; kk < 8; ++kk) pw8[kk] = projW[lane8 + kk];
    }
  }
  __syncthreads();

  auto encCompute = [&](int tt, const uint16_t* h0c, uint16_t* h0n){
    fx4 acc[4];
    #pragma unroll
    for (int gg = 0; gg < 4; ++gg)
      #pragma unroll
      for (int r = 0; r < 4; ++r) acc[gg][r] = e0r[gg][r];
    float xv[4][8];
    #pragma unroll
    for (int r = 0; r < 4; ++r){
      const float* xr = xh + ((size_t)(bq + r)*288 + tt)*8;
      #pragma unroll
      for (int kk = 0; kk < 8; ++kk) xv[r][kk] = xr[kk];
    }
    accK512_lds(acc, h0c + hoff, smem, lane8);
    #pragma unroll
    for (int gg = 0; gg < 4; ++gg)
      #pragma unroll
      for (int kk = 0; kk < 8; ++kk){
        float w = xw[gg][kk];
        #pragma unroll
        for (int r = 0; r < 4; ++r) acc[gg][r] += w * xv[r][kk];
      }
    pointwise(acc, creg, bq, u, col, h0n);
  };

  // emitY: blocks k=32..35; per half, wave wv4 covers 4 rows. Plain loads
  // (fresh after wait inv); single-writer out stores.
  auto emitY = [&](const uint16_t* h1cur, int tt){
    int rb = (g << 6) + ((k - 32) << 4) + (wv4 << 2);
    #pragma unroll 1
    for (int j = 0; j < 4; ++j){
      int b = rb + j;
      const uint16_t* hr = h1cur + (size_t)b*512 + lane8;
      float part = 0.f;
      #pragma unroll
      for (int kk = 0; kk < 8; ++kk) part += bf2f(hr[kk]) * pw8[kk];
      #pragma unroll
      for (int off = 32; off > 0; off >>= 1) part += __shfl_down(part, off);
      if (lane == 0) out[(size_t)b*288 + tt] = part + projB_val;
    }
  };

  // ============================ ENCODER ============================
  if (isL0){
    // t=0: h0_{-1} = zeros (buf1); no wait needed.
    encCompute(0, h0b[1], h0b[0]);
    arriveCnt(myline);                            // L0 count -> 16 when all
    #pragma unroll 1
    for (int t = 1; t < 288; ++t){
      // need h0_{t-1} (all L0) and L1 done consuming h0_{t-2} (lag-1 flow ctl)
      if (waitCnt(cntg, 16u*t, 16u*(t-1), abortf, &s_abort)) return;
      encCompute(t, h0b[(t-1)&1], h0b[t&1]);
      arriveCnt(myline);
    }
  } else {
    #pragma unroll 1
    for (int t = 0; t < 288; ++t){
      // need h0_t (all L0) and h1_{t-1} (all L1; also overwrite safety)
      if (waitCnt(cntg, 16u*(t+1), 16u*t, abortf, &s_abort)) return;
      fx4 acc[4];
      #pragma unroll
      for (int gg = 0; gg < 4; ++gg)
        #pragma unroll
        for (int r = 0; r < 4; ++r) acc[gg][r] = b1r[gg];
      accK512_lds(acc, h0b[t&1] + hoff, smem, lane8);               // Wih1e * h0_t
      accK512_lds(acc, h1b[(t-1)&1] + hoff, smem + 32768, lane8);   // Whh1e * h1_{t-1}
      pointwise(acc, creg, bq, u, col, h1b[t&1]);
      arriveCnt(myline);
    }
  }
  // L0 count = 16*288 (h0_287), L1 count = 16*288 (h1_287); c carries over.

  // ---- restage decoder weights + regs (block-local; own last use done) ----
  if (isL0){
    const uint4* s0 = (const uint4*)(Whh0d + (size_t)role*32768);
    const uint4* s1 = (const uint4*)(Wy    + (size_t)role*32768);
    for (int i = tid; i < 4096; i += NTHR){ smem4[i] = s0[i]; smem4[4096+i] = s1[i]; }
    #pragma unroll
    for (int gg = 0; gg < 4; ++gg){
      #pragma unroll
      for (int r = 0; r < 4; ++r)
        e0r[gg][r] = E0d[(size_t)(bq + r)*2048 + (gg << 9) + u];
      #pragma unroll
      for (int kk = 0; kk < 6; ++kk)
        xw[gg][kk] = decWih0[(size_t)((gg << 9) + u)*23 + 1 + kk];
      wc[gg] = wcol0[(gg << 9) + u];
    }
  } else {
    const uint4* s0 = (const uint4*)(Wih1d + (size_t)role*32768);
    const uint4* s1 = (const uint4*)(Whh1d + (size_t)role*32768);
    for (int i = tid; i < 4096; i += NTHR){ smem4[i] = s0[i]; smem4[4096+i] = s1[i]; }
    #pragma unroll
    for (int gg = 0; gg < 4; ++gg) b1r[gg] = b1d[(gg << 9) + u];
  }
  __syncthreads();

  auto decCompute = [&](int tt, const uint16_t* h0c, const uint16_t* h1c,
                        uint16_t* h0n){
    fx4 acc[4];
    #pragma unroll
    for (int gg = 0; gg < 4; ++gg)
      #pragma unroll
      for (int r = 0; r < 4; ++r) acc[gg][r] = e0r[gg][r];
    accK512_lds(acc, h0c + hoff, smem, lane8);                      // Whh0d
    if (tt > 0)
      accK512_lds(acc, h1c + hoff, smem + 32768, lane8);            // Wy
    float s[4];
    #pragma unroll
    for (int r = 0; r < 4; ++r) s[r] = (tt == 0) ? y0v[bq + r] : projB_val;
    float xv[4][6];
    #pragma unroll
    for (int r = 0; r < 4; ++r){
      const float* xr = xf + ((size_t)(bq + r)*288 + tt)*6;
      #pragma unroll
      for (int kk = 0; kk < 6; ++kk) xv[r][kk] = xr[kk];
    }
    #pragma unroll
    for (int gg = 0; gg < 4; ++gg){
      #pragma unroll
      for (int r = 0; r < 4; ++r) acc[gg][r] += wc[gg] * s[r];
      #pragma unroll
      for (int kk = 0; kk < 6; ++kk){
        float w = xw[gg][kk];
        #pragma unroll
        for (int r = 0; r < 4; ++r) acc[gg][r] += w * xv[r][kk];
      }
    }
    pointwise(acc, creg, bq, u, col, h0n);
  };

  // ============================ DECODER ============================
  // dec h_t is publish #(288+t+1); h_t -> buf[(288+t)&1] (parity continues).
  if (isL0){
    #pragma unroll 1
    for (int t = 0; t < 288; ++t){
      int s = 288 + t;
      // need dec h0_{t-1} (own set) and dec h1_{t-1} (L1; also flow ctl)
      if (waitCnt(cntg, 16u*s, 16u*s, abortf, &s_abort)) return;
      decCompute(t, h0b[(s-1)&1], h1b[(s-1)&1], h0b[s&1]);
      arriveCnt(myline);
    }
  } else {
    #pragma unroll 1
    for (int t = 0; t < 288; ++t){
      int s = 288 + t;
      // need h0_t (L0) and h1_{t-1} (own set: emitY + Whh1d + overwrite safety)
      if (waitCnt(cntg, 16u*(s+1), 16u*s, abortf, &s_abort)) return;
      if (k < 36 && t > 0) emitY(h1b[(s-1)&1], t - 1);
      fx4 acc[4];
      #pragma unroll
      for (int gg = 0; gg < 4; ++gg)
        #pragma unroll
        for (int r = 0; r < 4; ++r) acc[gg][r] = b1r[gg];
      accK512_lds(acc, h1b[(s-1)&1] + hoff, smem + 32768, lane8);   // Whh1d * h1_{t-1}
      accK512_lds(acc, h0b[s&1] + hoff, smem, lane8);               // Wih1d * h0_t
      pointwise(acc, creg, bq, u, col, h1b[s&1]);
      arriveCnt(myline);
    }
    // final y_287 from dec h1_287 (publish #576)
    if (k < 36){
      if (waitCnt(cntg, 0u, 16u*576u, abortf, &s_abort)) return;
      emitY(h1b[(288+287)&1], 287);
    }
  }
}

// ---------------- prep: frag-ordered bf16 weights (+Wy), emb+bias folds ----
#define PREP_S 1048576
#define PREP_TOTAL (7*PREP_S + 1048576 + 6144)

__global__ void __launch_bounds__(256)
prep_kernel(const float* __restrict__ encWih0, const float* __restrict__ encWhh0,
            const float* __restrict__ encWih1, const float* __restrict__ encWhh1,
            const float* __restrict__ decWih0, const float* __restrict__ decWhh0,
            const float* __restrict__ decWih1, const float* __restrict__ decWhh1,
            const float* __restrict__ encbih0, const float* __restrict__ encbhh0,
            const float* __restrict__ encbih1, const float* __restrict__ encbhh1,
            const float* __restrict__ decbih0, const float* __restrict__ decbhh0,
            const float* __restrict__ decbih1, const float* __restrict__ decbhh1,
            const float* __restrict__ projW, const float* __restrict__ emb,
            const int* __restrict__ turb,
            uint16_t* Whh0e, uint16_t* Wih1e, uint16_t* Whh1e,
            uint16_t* Whh0d, uint16_t* Wih1d, uint16_t* Whh1d, uint16_t* Wyp,
            float* E0e, float* E0d, float* b1e, float* b1d, float* wcol0)
{
  int i = blockIdx.x*256 + threadIdx.x;
  if (i >= PREP_TOTAL) return;
  if (i < 7*PREP_S){
    // fragment reorder: dest = role*32768 + gate*8192 + kc*512 + lane*8 + j
    // value = W[gate*512 + role*16 + (lane&15)][kc*32 + (lane>>4)*8 + j]
    int w = i >> 20, r = i & (PREP_S - 1);
    int role = r >> 15;
    int rem  = r & 32767;
    int gate = rem >> 13;
    int kc   = (rem >> 9) & 15;
    int ln   = (rem >> 3) & 63;
    int j    = rem & 7;
    int c = ln & 15, q = ln >> 4;
    int row  = (gate << 9) + (role << 4) + c;
    int colk = (kc << 5) + (q << 3) + j;
    float v;
    if (w == 6){
      v = decWih0[(size_t)row*23] * projW[colk];     // Wy = wcol0 (x) projW
    } else {
      const float* src = (w==0)?encWhh0:(w==1)?encWih1:(w==2)?encWhh1:
                         (w==3)?decWhh0:(w==4)?decWih1:decWhh1;
      v = src[(size_t)row*512 + colk];
    }
    uint16_t* dst = (w==0)?Whh0e:(w==1)?Wih1e:(w==2)?Whh1e:
                    (w==3)?Whh0d:(w==4)?Wih1d:(w==5)?Whh1d:Wyp;
    dst[r] = f2bf(v);
  } else if (i < 7*PREP_S + 524288){
    int r = i - 7*PREP_S; int b = r >> 11, j = r & 2047;
    float s = encbih0[j] + encbhh0[j];
    const float* e = emb + (size_t)turb[b]*16;
    const float* wr = encWih0 + (size_t)j*24 + 8;
    #pragma unroll
    for (int m = 0; m < 16; ++m) s += e[m]*wr[m];
    E0e[r] = s;
  } else if (i < 7*PREP_S + 1048576){
    int r = i - 7*PREP_S - 524288; int b = r >> 11, j = r & 2047;
    float s = decbih0[j] + decbhh0[j];
    const float* e = emb + (size_t)turb[b]*16;
    const float* wr = decWih0 + (size_t)j*23 + 7;
    #pragma unroll
    for (int m = 0; m < 16; ++m) s += e[m]*wr[m];
    E0d[r] = s;
  } else {
    int r = i - 7*PREP_S - 1048576;
    if (r < 2048)      b1e[r] = encbih1[r] + encbhh1[r];
    else if (r < 4096){ int j = r - 2048; b1d[j] = decbih1[j] + decbhh1[j]; }
    else              { int j = r - 4096; wcol0[j] = decWih0[(size_t)j*23]; }
  }
}

// ---------------------------------------------------------------------------
extern "C" void kernel_launch(void* const* d_in, const int* in_sizes, int n_in,
                              void* d_out, int out_size, void* d_ws, size_t ws_size,
                              hipStream_t stream)
{
  const float* xh      = (const float*)d_in[0];
  const float* xf      = (const float*)d_in[1];
  const float* y0v     = (const float*)d_in[2];
  const int*   turb    = (const int*)d_in[3];
  const float* emb     = (const float*)d_in[5];
  const float* encWih0 = (const float*)d_in[6];
  const float* encWhh0 = (const float*)d_in[7];
  const float* encbih0 = (const float*)d_in[8];
  const float* encbhh0 = (const float*)d_in[9];
  const float* encWih1 = (const float*)d_in[10];
  const float* encWhh1 = (const float*)d_in[11];
  const float* encbih1 = (const float*)d_in[12];
  const float* encbhh1 = (const float*)d_in[13];
  const float* decWih0 = (const float*)d_in[14];
  const float* decWhh0 = (const float*)d_in[15];
  const float* decbih0 = (const float*)d_in[16];
  const float* decbhh0 = (const float*)d_in[17];
  const float* decWih1 = (const float*)d_in[18];
  const float* decWhh1 = (const float*)d_in[19];
  const float* decbih1 = (const float*)d_in[20];
  const float* decbhh1 = (const float*)d_in[21];
  const float* projW   = (const float*)d_in[22];
  const float* projB   = (const float*)d_in[23];
  float* out = (float*)d_out;

  char* ws = (char*)d_ws;
  constexpr size_t SZW = (size_t)2048*512*2;        // 2 MiB per matrix
  constexpr size_t OFF_Whh0e = 0;
  constexpr size_t OFF_Wih1e = SZW;
  constexpr size_t OFF_Whh1e = 2*SZW;
  constexpr size_t OFF_Whh0d = 3*SZW;
  constexpr size_t OFF_Wih1d = 4*SZW;
  constexpr size_t OFF_Whh1d = 5*SZW;
  constexpr size_t OFF_Wy    = 6*SZW;
  constexpr size_t OFF_E0e   = 7*SZW;
  constexpr size_t OFF_E0d   = OFF_E0e + 2097152;
  constexpr size_t OFF_b1e   = OFF_E0d + 2097152;
  constexpr size_t OFF_b1d   = OFF_b1e + 8192;
  constexpr size_t OFF_wcol0 = OFF_b1d + 8192;
  constexpr size_t OFF_h0    = OFF_wcol0 + 8192;
  constexpr size_t OFF_h1    = OFF_h0 + 524288;
  constexpr size_t OFF_cnt   = OFF_h1 + 524288;
  constexpr size_t ZERO_BYTES = 2*524288 + 2048;    // h0,h1 ping-pong + counters+abort

  uint16_t* Whh0e = (uint16_t*)(ws + OFF_Whh0e);
  uint16_t* Wih1e = (uint16_t*)(ws + OFF_Wih1e);
  uint16_t* Whh1e = (uint16_t*)(ws + OFF_Whh1e);
  uint16_t* Whh0d = (uint16_t*)(ws + OFF_Whh0d);
  uint16_t* Wih1d = (uint16_t*)(ws + OFF_Wih1d);
  uint16_t* Whh1d = (uint16_t*)(ws + OFF_Whh1d);
  uint16_t* Wyp   = (uint16_t*)(ws + OFF_Wy);
  float* E0e   = (float*)(ws + OFF_E0e);
  float* E0d   = (float*)(ws + OFF_E0d);
  float* b1e   = (float*)(ws + OFF_b1e);
  float* b1d   = (float*)(ws + OFF_b1d);
  float* wcol0 = (float*)(ws + OFF_wcol0);
  uint16_t* h0p = (uint16_t*)(ws + OFF_h0);
  uint16_t* h1p = (uint16_t*)(ws + OFF_h1);
  unsigned* cntp = (unsigned*)(ws + OFF_cnt);

  hipMemsetAsync(ws + OFF_h0, 0, ZERO_BYTES, stream);

  prep_kernel<<<dim3((PREP_TOTAL + 255)/256), dim3(256), 0, stream>>>(
      encWih0, encWhh0, encWih1, encWhh1, decWih0, decWhh0, decWih1, decWhh1,
      encbih0, encbhh0, encbih1, encbhh1, decbih0, decbhh0, decbih1, decbhh1,
      projW, emb, turb,
      Whh0e, Wih1e, Whh1e, Whh0d, Wih1d, Whh1d, Wyp,
      E0e, E0d, b1e, b1d, wcol0);

  // Plain launch (proven R11/R14/R15/R16). 128 blocks on 256 CUs @ 1 block/CU
  // -> co-residency with 2x slack; every wait is abort-guarded.
  seq2seq_main<<<dim3(NBLK), dim3(NTHR), 0, stream>>>(
      Whh0e, Wih1e, Whh1e, Whh0d, Wih1d, Whh1d, Wyp,
      E0e, E0d, b1e, b1d, wcol0,
      h0p, h1p, xh, xf, y0v,
      encWih0, decWih0, projW, projB,
      out, cntp);
}

// Round 11
// 10069.282 us; speedup vs baseline: 1.0434x; 1.0362x over previous
//
#include <hip/hip_runtime.h>
#include <stdint.h>

// ---------------------------------------------------------------------------
// R18 = R15 (9.95ms, best) + three data-path fixes (math value-identical):
//   1) accK512: batch all 16 A-fragment b128 loads into regs BEFORE the MFMA
//      loop -> one pipelined refill (~900cyc) instead of a serialized
//      miss-per-kc chain after each barrier's buffer_inv (2 waves/SIMD can't
//      hide interleaved misses).
//   2) pointwise: pack 4 bf16 cols via 2 shuffle levels -> one system-scope
//      b64 atomic store per 4 lanes (4x fewer transactions than R11's plan,
//      2x fewer than R15) -> shorter store-drain before arrival.
//   3) x prefetch: load next step's xh/xf rows into REGISTERS before the
//      barrier wait (miss overlaps the spin; regs survive the inv).
//   Sync structure byte-identical to R15 (leader/go barrier, 2 bars/dec step,
//   1 bar/enc step): three sync-topology variants (R15/16/17) all landed at
//   10+-0.5ms -> the lever is the data path, not the barrier graph.
//   Coherence model (established R11-R17): system-scope stores/loads act at
//   the fabric coherence point; agent RMWs too; plain loads are L2-cached and
//   need acquire-inv after detect; h writes MUST bypass L2 (system scope).
// ---------------------------------------------------------------------------

typedef __attribute__((ext_vector_type(8))) short bfx8;   // 8 bf16 (4 VGPRs)
typedef __attribute__((ext_vector_type(4))) float fx4;

#define NBLK 128
#define NTHR 512
#define BH   (256*512)

__device__ __forceinline__ unsigned short f2bf(float f){
  unsigned u = __float_as_uint(f);
  u += 0x7FFFu + ((u >> 16) & 1u);          // RNE
  return (unsigned short)(u >> 16);
}
__device__ __forceinline__ float bf2f(unsigned short b){
  return __uint_as_float(((unsigned)b) << 16);
}
__device__ __forceinline__ float sigm(float x){ return 1.0f/(1.0f + __expf(-x)); }
__device__ __forceinline__ float tanhf_(float x){
  x = fminf(12.0f, fmaxf(-12.0f, x));
  float e = __expf(2.0f*x);
  return (e - 1.0f)/(e + 1.0f);
}

// 64-block supergroup barrier, leader/go structure (R15-proven).
__device__ __forceinline__ bool groupbar(unsigned* cntg, int sub, unsigned gen,
                                         unsigned* go, bool leader,
                                         unsigned* abortf, volatile unsigned* s_abort){
  __syncthreads();
  if (threadIdx.x == 0){
    __hip_atomic_fetch_add(cntg + sub*32, 1u, __ATOMIC_RELAXED, __HIP_MEMORY_SCOPE_AGENT);
    const unsigned target = gen*16u;
    unsigned spins = 0;
    if (leader){
      for (;;){
        unsigned v0 = __hip_atomic_fetch_add(cntg +  0, 0u, __ATOMIC_RELAXED, __HIP_MEMORY_SCOPE_AGENT);
        unsigned v1 = __hip_atomic_fetch_add(cntg + 32, 0u, __ATOMIC_RELAXED, __HIP_MEMORY_SCOPE_AGENT);
        unsigned v2 = __hip_atomic_fetch_add(cntg + 64, 0u, __ATOMIC_RELAXED, __HIP_MEMORY_SCOPE_AGENT);
        unsigned v3 = __hip_atomic_fetch_add(cntg + 96, 0u, __ATOMIC_RELAXED, __HIP_MEMORY_SCOPE_AGENT);
        if (v0 >= target && v1 >= target && v2 >= target && v3 >= target) break;
        if (((++spins) & 1023u) == 0u){
          if (__hip_atomic_load(abortf, __ATOMIC_RELAXED, __HIP_MEMORY_SCOPE_AGENT) != 0u){
            *s_abort = 1u; break;
          }
          if (spins > (1u << 20)){
            __hip_atomic_store(abortf, 1u, __ATOMIC_RELAXED, __HIP_MEMORY_SCOPE_AGENT);
            *s_abort = 1u; break;
          }
        }
        __builtin_amdgcn_s_sleep(2);
      }
      __hip_atomic_store(go, gen, __ATOMIC_RELAXED, __HIP_MEMORY_SCOPE_SYSTEM);
    } else {
      while (__hip_atomic_load(go, __ATOMIC_RELAXED, __HIP_MEMORY_SCOPE_SYSTEM) < gen){
        if (((++spins) & 1023u) == 0u){
          if (__hip_atomic_load(abortf, __ATOMIC_RELAXED, __HIP_MEMORY_SCOPE_AGENT) != 0u){
            *s_abort = 1u; break;
          }
          if (spins > (1u << 20)){
            __hip_atomic_store(abortf, 1u, __ATOMIC_RELAXED, __HIP_MEMORY_SCOPE_AGENT);
            *s_abort = 1u; break;
          }
        }
        __builtin_amdgcn_s_sleep(2);
      }
    }
    (void)__hip_atomic_load(cntg, __ATOMIC_ACQUIRE, __HIP_MEMORY_SCOPE_AGENT);  // buffer_inv
  }
  __syncthreads();
  return *s_abort != 0u;
}

// K=512 accumulate. A-fragments are BATCH-loaded into registers first (16
// independent b128 loads -> one pipelined refill after the barrier's inv),
// then 64 MFMAs stream against LDS-resident B fragments. Value-identical to
// the interleaved form (same MFMA order).
__device__ __forceinline__ void accK512_lds(fx4* acc, const uint16_t* aq,
                                            const uint16_t* wl, int lane8){
  bfx8 a[16];
  #pragma unroll
  for (int kc = 0; kc < 16; ++kc) a[kc] = *(const bfx8*)(aq + kc*32);
  #pragma unroll
  for (int kc = 0; kc < 16; ++kc){
    acc[0] = __builtin_amdgcn_mfma_f32_16x16x32_bf16(a[kc], *(const bfx8*)(wl +         kc*512 + lane8), acc[0], 0, 0, 0);
    acc[1] = __builtin_amdgcn_mfma_f32_16x16x32_bf16(a[kc], *(const bfx8*)(wl +  8192 + kc*512 + lane8), acc[1], 0, 0, 0);
    acc[2] = __builtin_amdgcn_mfma_f32_16x16x32_bf16(a[kc], *(const bfx8*)(wl + 16384 + kc*512 + lane8), acc[2], 0, 0, 0);
    acc[3] = __builtin_amdgcn_mfma_f32_16x16x32_bf16(a[kc], *(const bfx8*)(wl + 24576 + kc*512 + lane8), acc[3], 0, 0, 0);
  }
}

// LSTM pointwise; h store = 4 cols packed into one SYSTEM-scope b64 store
// (lanes col%4==0). 2 shuffle levels; write-through to the coherence point.
__device__ __forceinline__ void pointwise(fx4* acc, fx4& creg, int bq, int u,
                                          int col, uint16_t* hout){
  #pragma unroll
  for (int r = 0; r < 4; ++r){
    float iv = sigm(acc[0][r]);
    float fv = sigm(acc[1][r]);
    float gv = tanhf_(acc[2][r]);
    float ov = sigm(acc[3][r]);
    float cn = fv * creg[r] + iv * gv;
    creg[r] = cn;
    unsigned hb = (unsigned)f2bf(ov * tanhf_(cn));
    unsigned p2 = hb | (__shfl_xor(hb, 1) << 16);   // even col: h[c]|h[c+1]
    unsigned hi = __shfl_xor(p2, 2);                // col%4==0: h[c+2]|h[c+3]
    if ((col & 3) == 0){
      unsigned long long v = (unsigned long long)p2 | ((unsigned long long)hi << 32);
      __hip_atomic_store((unsigned long long*)(hout + (size_t)(bq + r)*512 + u), v,
                         __ATOMIC_RELAXED, __HIP_MEMORY_SCOPE_SYSTEM);
    }
  }
}

__global__ void __launch_bounds__(NTHR, 2)
seq2seq_main(const uint16_t* __restrict__ Whh0e, const uint16_t* __restrict__ Wih1e,
             const uint16_t* __restrict__ Whh1e, const uint16_t* __restrict__ Whh0d,
             const uint16_t* __restrict__ Wih1d, const uint16_t* __restrict__ Whh1d,
             const uint16_t* __restrict__ Wy,
             const float* __restrict__ E0e, const float* __restrict__ E0d,
             const float* __restrict__ b1e, const float* __restrict__ b1d,
             const float* __restrict__ wcol0,
             uint16_t* h0buf, uint16_t* h1buf,
             const float* __restrict__ xh, const float* __restrict__ xf,
             const float* __restrict__ y0v,
             const float* __restrict__ encWih0, const float* __restrict__ decWih0,
             const float* __restrict__ projW, const float* __restrict__ projB,
             float* out, unsigned* cntBase)
{
  __shared__ uint4 smem4[8192];                 // 128 KiB static LDS
  __shared__ unsigned s_abort;
  uint16_t* smem = (uint16_t*)smem4;

  const int tid  = threadIdx.x;
  const int lane = tid & 63;
  const int wvi  = tid >> 6;                    // wave in block, 0..7
  const int gh   = wvi >> 2;                    // batch-half within supergroup
  const int wv4  = wvi & 3;                     // M-tile index within half
  const int sg   = blockIdx.x >> 6;             // supergroup (128 batch rows)
  const int k    = blockIdx.x & 63;             // role: 0..31 L0, 32..63 L1
  const bool isL0 = (k < 32);
  const int role = isL0 ? k : k - 32;           // u-slice index, 0..31
  const int col  = lane & 15;
  const int quad = lane >> 4;
  const int g    = (sg << 1) + gh;              // logical 64-row group, 0..3
  const int rowbase = (g << 6) + (wv4 << 4);    // wave's 16-row M-tile base
  const int bq   = rowbase + (quad << 2);
  const int u    = (role << 4) + col;
  const int lane8 = lane << 3;
  unsigned* cntg = cntBase + (size_t)sg * 128;  // 4 counters x 128B / supergroup
  unsigned* abortf = cntBase + 256;             // abort flag (own line, zeroed)
  unsigned* go     = cntBase + 288 + sg*32;     // go word (own line, zeroed)
  const bool leader = (k == 0);
  const int sub  = k >> 4;
  unsigned gen = 0;
  fx4 creg = {0.f, 0.f, 0.f, 0.f};              // c0 (L0) or c1 (L1)
  const float projB_val = projB[0];
  const int hoff = (rowbase + col)*512 + (quad << 3);

  if (tid == 0) s_abort = 0u;

  uint16_t *h0A = h0buf, *h0B = h0buf + BH;
  uint16_t *h1A = h1buf, *h1B = h1buf + BH;

  // ---- stage encoder weight slices into LDS ----
  if (isL0){
    const uint4* s0 = (const uint4*)(Whh0e + (size_t)role*32768);
    for (int i = tid; i < 4096; i += NTHR) smem4[i] = s0[i];
  } else {
    const uint4* s0 = (const uint4*)(Wih1e + (size_t)role*32768);
    const uint4* s1 = (const uint4*)(Whh1e + (size_t)role*32768);
    for (int i = tid; i < 4096; i += NTHR){ smem4[i] = s0[i]; smem4[4096+i] = s1[i]; }
  }

  // ---- hoist per-lane constants into registers ----
  float e0r[4][4], xw[4][8], wc[4], b1r[4], pw8[8];
  if (isL0){
    #pragma unroll
    for (int gg = 0; gg < 4; ++gg){
      #pragma unroll
      for (int r = 0; r < 4; ++r)
        e0r[gg][r] = E0e[(size_t)(bq + r)*2048 + (gg << 9) + u];
      #pragma unroll
      for (int kk = 0; kk < 8; ++kk)
        xw[gg][kk] = encWih0[(size_t)((gg << 9) + u)*24 + kk];
    }
  } else {
    #pragma unroll
    for (int gg = 0; gg < 4; ++gg) b1r[gg] = b1e[(gg << 9) + u];
    if (k < 36){                                // emitY blocks k=32..35
      #pragma unroll
      for (int kk = 0; kk < 8; ++kk) pw8[kk] = projW[lane8 + kk];
    }
  }
  __syncthreads();

  float xve[4][8];                              // enc x prefetch (L0 only)
  auto loadXe = [&](int tt){
    #pragma unroll
    for (int r = 0; r < 4; ++r){
      const float* xr = xh + ((size_t)(bq + r)*288 + tt)*8;
      #pragma unroll
      for (int kk = 0; kk < 8; ++kk) xve[r][kk] = xr[kk];
    }
  };

  auto encCompute = [&](const uint16_t* h0c, uint16_t* h0n){
    fx4 acc[4];
    #pragma unroll
    for (int gg = 0; gg < 4; ++gg)
      #pragma unroll
      for (int r = 0; r < 4; ++r) acc[gg][r] = e0r[gg][r];
    accK512_lds(acc, h0c + hoff, smem, lane8);
    #pragma unroll
    for (int gg = 0; gg < 4; ++gg)
      #pragma unroll
      for (int kk = 0; kk < 8; ++kk){
        float w = xw[gg][kk];
        #pragma unroll
        for (int r = 0; r < 4; ++r) acc[gg][r] += w * xve[r][kk];
      }
    pointwise(acc, creg, bq, u, col, h0n);
  };

  // emitY: blocks k=32..35; per half, wave wv4 covers 4 rows. Plain loads
  // (fresh after barrier inv); single-writer out stores.
  auto emitY = [&](const uint16_t* h1cur, int tt){
    int rb = (g << 6) + ((k - 32) << 4) + (wv4 << 2);
    #pragma unroll 1
    for (int j = 0; j < 4; ++j){
      int b = rb + j;
      const uint16_t* hr = h1cur + (size_t)b*512 + lane8;
      float part = 0.f;
      #pragma unroll
      for (int kk = 0; kk < 8; ++kk) part += bf2f(hr[kk]) * pw8[kk];
      #pragma unroll
      for (int off = 32; off > 0; off >>= 1) part += __shfl_down(part, off);
      if (lane == 0) out[(size_t)b*288 + tt] = part + projB_val;
    }
  };

  // ---- prologue: enc L0 t=0 (h_{-1}=0 via memset) ----
  if (isL0){
    loadXe(0);
    encCompute(h0A, h0B);
    loadXe(1);                                  // prefetch x_1, overlaps barrier
  }
  if (groupbar(cntg, sub, ++gen, go, leader, abortf, &s_abort)) return;
  { uint16_t* t_ = h0A; h0A = h0B; h0B = t_; }   // h0A = h0_0

  // ---- encoder: 1 barrier/step; L1_t || L0_{t+1} ----
  #pragma unroll 1
  for (int t = 0; t < 288; ++t){
    if (isL0){
      if (t < 287){
        encCompute(h0A, h0B);                   // step t+1 (uses xve = x_{t+1})
        if (t < 286) loadXe(t + 2);             // prefetch x_{t+2} before bar
      }
    } else {
      fx4 acc[4];
      #pragma unroll
      for (int gg = 0; gg < 4; ++gg)
        #pragma unroll
        for (int r = 0; r < 4; ++r) acc[gg][r] = b1r[gg];
      accK512_lds(acc, h0A + hoff, smem, lane8);            // Wih1e * h0_t
      accK512_lds(acc, h1A + hoff, smem + 32768, lane8);    // Whh1e * h1_{t-1}
      pointwise(acc, creg, bq, u, col, h1B);
    }
    if (groupbar(cntg, sub, ++gen, go, leader, abortf, &s_abort)) return;
    { uint16_t* t_ = h1A; h1A = h1B; h1B = t_; }
    if (t < 287){ uint16_t* t_ = h0A; h0A = h0B; h0B = t_; }
  }
  // h0A = h0_287, h1A = h1_287; c continues into decoder.

  // ---- restage decoder weights + regs (block-local) ----
  float xvd[4][6];                              // dec x prefetch (L0 only)
  auto loadXd = [&](int tt){
    #pragma unroll
    for (int r = 0; r < 4; ++r){
      const float* xr = xf + ((size_t)(bq + r)*288 + tt)*6;
      #pragma unroll
      for (int kk = 0; kk < 6; ++kk) xvd[r][kk] = xr[kk];
    }
  };
  if (isL0){
    const uint4* s0 = (const uint4*)(Whh0d + (size_t)role*32768);
    const uint4* s1 = (const uint4*)(Wy    + (size_t)role*32768);
    for (int i = tid; i < 4096; i += NTHR){ smem4[i] = s0[i]; smem4[4096+i] = s1[i]; }
    #pragma unroll
    for (int gg = 0; gg < 4; ++gg){
      #pragma unroll
      for (int r = 0; r < 4; ++r)
        e0r[gg][r] = E0d[(size_t)(bq + r)*2048 + (gg << 9) + u];
      #pragma unroll
      for (int kk = 0; kk < 6; ++kk)
        xw[gg][kk] = decWih0[(size_t)((gg << 9) + u)*23 + 1 + kk];
      wc[gg] = wcol0[(gg << 9) + u];
    }
    loadXd(0);
  } else {
    const uint4* s0 = (const uint4*)(Wih1d + (size_t)role*32768);
    const uint4* s1 = (const uint4*)(Whh1d + (size_t)role*32768);
    for (int i = tid; i < 4096; i += NTHR){ smem4[i] = s0[i]; smem4[4096+i] = s1[i]; }
    #pragma unroll
    for (int gg = 0; gg < 4; ++gg) b1r[gg] = b1d[(gg << 9) + u];
  }
  __syncthreads();

  auto decCompute = [&](int tt, const uint16_t* h0c, const uint16_t* h1c,
                        uint16_t* h0n){
    fx4 acc[4];
    #pragma unroll
    for (int gg = 0; gg < 4; ++gg)
      #pragma unroll
      for (int r = 0; r < 4; ++r) acc[gg][r] = e0r[gg][r];
    accK512_lds(acc, h0c + hoff, smem, lane8);              // Whh0d
    if (tt > 0)
      accK512_lds(acc, h1c + hoff, smem + 32768, lane8);    // Wy
    float s[4];
    #pragma unroll
    for (int r = 0; r < 4; ++r) s[r] = (tt == 0) ? y0v[bq + r] : projB_val;
    #pragma unroll
    for (int gg = 0; gg < 4; ++gg){
      #pragma unroll
      for (int r = 0; r < 4; ++r) acc[gg][r] += wc[gg] * s[r];
      #pragma unroll
      for (int kk = 0; kk < 6; ++kk){
        float w = xw[gg][kk];
        #pragma unroll
        for (int r = 0; r < 4; ++r) acc[gg][r] += w * xvd[r][kk];
      }
    }
    pointwise(acc, creg, bq, u, col, h0n);
  };

  // ---- decoder: 2 barriers/step (R15 structure) ----
  #pragma unroll 1
  for (int t = 0; t < 288; ++t){
    if (isL0){
      decCompute(t, h0A, h1A, h0B);             // uses xvd = x_t
      if (t < 287) loadXd(t + 1);               // prefetch x_{t+1} before bar
    } else if (k < 36 && t > 0){
      emitY(h1A, t - 1);
    }
    if (groupbar(cntg, sub, ++gen, go, leader, abortf, &s_abort)) return;
    if (!isL0){
      fx4 acc[4];
      #pragma unroll
      for (int gg = 0; gg < 4; ++gg)
        #pragma unroll
        for (int r = 0; r < 4; ++r) acc[gg][r] = b1r[gg];
      accK512_lds(acc, h1A + hoff, smem + 32768, lane8);    // Whh1d * h1_{t-1}
      accK512_lds(acc, h0B + hoff, smem, lane8);            // Wih1d * h0_t
      pointwise(acc, creg, bq, u, col, h1B);
    }
    if (groupbar(cntg, sub, ++gen, go, leader, abortf, &s_abort)) return;
    { uint16_t* t_ = h0A; h0A = h0B; h0B = t_; }
    { uint16_t* t_ = h1A; h1A = h1B; h1B = t_; }
  }

  // final y_287 (h1A = h1_287, published by last barrier)
  if (!isL0 && k < 36) emitY(h1A, 287);
}

// ---------------- prep: frag-ordered bf16 weights (+Wy), emb+bias folds ----
#define PREP_S 1048576
#define PREP_TOTAL (7*PREP_S + 1048576 + 6144)

__global__ void __launch_bounds__(256)
prep_kernel(const float* __restrict__ encWih0, const float* __restrict__ encWhh0,
            const float* __restrict__ encWih1, const float* __restrict__ encWhh1,
            const float* __restrict__ decWih0, const float* __restrict__ decWhh0,
            const float* __restrict__ decWih1, const float* __restrict__ decWhh1,
            const float* __restrict__ encbih0, const float* __restrict__ encbhh0,
            const float* __restrict__ encbih1, const float* __restrict__ encbhh1,
            const float* __restrict__ decbih0, const float* __restrict__ decbhh0,
            const float* __restrict__ decbih1, const float* __restrict__ decbhh1,
            const float* __restrict__ projW, const float* __restrict__ emb,
            const int* __restrict__ turb,
            uint16_t* Whh0e, uint16_t* Wih1e, uint16_t* Whh1e,
            uint16_t* Whh0d, uint16_t* Wih1d, uint16_t* Whh1d, uint16_t* Wyp,
            float* E0e, float* E0d, float* b1e, float* b1d, float* wcol0)
{
  int i = blockIdx.x*256 + threadIdx.x;
  if (i >= PREP_TOTAL) return;
  if (i < 7*PREP_S){
    // fragment reorder: dest = role*32768 + gate*8192 + kc*512 + lane*8 + j
    // value = W[gate*512 + role*16 + (lane&15)][kc*32 + (lane>>4)*8 + j]
    int w = i >> 20, r = i & (PREP_S - 1);
    int role = r >> 15;
    int rem  = r & 32767;
    int gate = rem >> 13;
    int kc   = (rem >> 9) & 15;
    int ln   = (rem >> 3) & 63;
    int j    = rem & 7;
    int c = ln & 15, q = ln >> 4;
    int row  = (gate << 9) + (role << 4) + c;
    int colk = (kc << 5) + (q << 3) + j;
    float v;
    if (w == 6){
      v = decWih0[(size_t)row*23] * projW[colk];     // Wy = wcol0 (x) projW
    } else {
      const float* src = (w==0)?encWhh0:(w==1)?encWih1:(w==2)?encWhh1:
                         (w==3)?decWhh0:(w==4)?decWih1:decWhh1;
      v = src[(size_t)row*512 + colk];
    }
    uint16_t* dst = (w==0)?Whh0e:(w==1)?Wih1e:(w==2)?Whh1e:
                    (w==3)?Whh0d:(w==4)?Wih1d:(w==5)?Whh1d:Wyp;
    dst[r] = f2bf(v);
  } else if (i < 7*PREP_S + 524288){
    int r = i - 7*PREP_S; int b = r >> 11, j = r & 2047;
    float s = encbih0[j] + encbhh0[j];
    const float* e = emb + (size_t)turb[b]*16;
    const float* wr = encWih0 + (size_t)j*24 + 8;
    #pragma unroll
    for (int m = 0; m < 16; ++m) s += e[m]*wr[m];
    E0e[r] = s;
  } else if (i < 7*PREP_S + 1048576){
    int r = i - 7*PREP_S - 524288; int b = r >> 11, j = r & 2047;
    float s = decbih0[j] + decbhh0[j];
    const float* e = emb + (size_t)turb[b]*16;
    const float* wr = decWih0 + (size_t)j*23 + 7;
    #pragma unroll
    for (int m = 0; m < 16; ++m) s += e[m]*wr[m];
    E0d[r] = s;
  } else {
    int r = i - 7*PREP_S - 1048576;
    if (r < 2048)      b1e[r] = encbih1[r] + encbhh1[r];
    else if (r < 4096){ int j = r - 2048; b1d[j] = decbih1[j] + decbhh1[j]; }
    else              { int j = r - 4096; wcol0[j] = decWih0[(size_t)j*23]; }
  }
}

// ---------------------------------------------------------------------------
extern "C" void kernel_launch(void* const* d_in, const int* in_sizes, int n_in,
                              void* d_out, int out_size, void* d_ws, size_t ws_size,
                              hipStream_t stream)
{
  const float* xh      = (const float*)d_in[0];
  const float* xf      = (const float*)d_in[1];
  const float* y0v     = (const float*)d_in[2];
  const int*   turb    = (const int*)d_in[3];
  const float* emb     = (const float*)d_in[5];
  const float* encWih0 = (const float*)d_in[6];
  const float* encWhh0 = (const float*)d_in[7];
  const float* encbih0 = (const float*)d_in[8];
  const float* encbhh0 = (const float*)d_in[9];
  const float* encWih1 = (const float*)d_in[10];
  const float* encWhh1 = (const float*)d_in[11];
  const float* encbih1 = (const float*)d_in[12];
  const float* encbhh1 = (const float*)d_in[13];
  const float* decWih0 = (const float*)d_in[14];
  const float* decWhh0 = (const float*)d_in[15];
  const float* decbih0 = (const float*)d_in[16];
  const float* decbhh0 = (const float*)d_in[17];
  const float* decWih1 = (const float*)d_in[18];
  const float* decWhh1 = (const float*)d_in[19];
  const float* decbih1 = (const float*)d_in[20];
  const float* decbhh1 = (const float*)d_in[21];
  const float* projW   = (const float*)d_in[22];
  const float* projB   = (const float*)d_in[23];
  float* out = (float*)d_out;

  char* ws = (char*)d_ws;
  constexpr size_t SZW = (size_t)2048*512*2;        // 2 MiB per matrix
  constexpr size_t OFF_Whh0e = 0;
  constexpr size_t OFF_Wih1e = SZW;
  constexpr size_t OFF_Whh1e = 2*SZW;
  constexpr size_t OFF_Whh0d = 3*SZW;
  constexpr size_t OFF_Wih1d = 4*SZW;
  constexpr size_t OFF_Whh1d = 5*SZW;
  constexpr size_t OFF_Wy    = 6*SZW;
  constexpr size_t OFF_E0e   = 7*SZW;
  constexpr size_t OFF_E0d   = OFF_E0e + 2097152;
  constexpr size_t OFF_b1e   = OFF_E0d + 2097152;
  constexpr size_t OFF_b1d   = OFF_b1e + 8192;
  constexpr size_t OFF_wcol0 = OFF_b1d + 8192;
  constexpr size_t OFF_h0    = OFF_wcol0 + 8192;
  constexpr size_t OFF_h1    = OFF_h0 + 524288;
  constexpr size_t OFF_cnt   = OFF_h1 + 524288;
  constexpr size_t ZERO_BYTES = 2*524288 + 2048;    // h0,h1 ping-pong + counters+go+abort

  uint16_t* Whh0e = (uint16_t*)(ws + OFF_Whh0e);
  uint16_t* Wih1e = (uint16_t*)(ws + OFF_Wih1e);
  uint16_t* Whh1e = (uint16_t*)(ws + OFF_Whh1e);
  uint16_t* Whh0d = (uint16_t*)(ws + OFF_Whh0d);
  uint16_t* Wih1d = (uint16_t*)(ws + OFF_Wih1d);
  uint16_t* Whh1d = (uint16_t*)(ws + OFF_Whh1d);
  uint16_t* Wyp   = (uint16_t*)(ws + OFF_Wy);
  float* E0e   = (float*)(ws + OFF_E0e);
  float* E0d   = (float*)(ws + OFF_E0d);
  float* b1e   = (float*)(ws + OFF_b1e);
  float* b1d   = (float*)(ws + OFF_b1d);
  float* wcol0 = (float*)(ws + OFF_wcol0);
  uint16_t* h0p = (uint16_t*)(ws + OFF_h0);
  uint16_t* h1p = (uint16_t*)(ws + OFF_h1);
  unsigned* cntp = (unsigned*)(ws + OFF_cnt);

  hipMemsetAsync(ws + OFF_h0, 0, ZERO_BYTES, stream);

  prep_kernel<<<dim3((PREP_TOTAL + 255)/256), dim3(256), 0, stream>>>(
      encWih0, encWhh0, encWih1, encWhh1, decWih0, decWhh0, decWih1, decWhh1,
      encbih0, encbhh0, encbih1, encbhh1, decbih0, decbhh0, decbih1, decbhh1,
      projW, emb, turb,
      Whh0e, Wih1e, Whh1e, Whh0d, Wih1d, Whh1d, Wyp,
      E0e, E0d, b1e, b1d, wcol0);

  // Plain launch (proven R11/R14/R15). 128 blocks on 256 CUs @ 1 block/CU ->
  // co-residency with 2x slack; barrier spin is abort-guarded.
  seq2seq_main<<<dim3(NBLK), dim3(NTHR), 0, stream>>>(
      Whh0e, Wih1e, Whh1e, Whh0d, Wih1d, Whh1d, Wyp,
      E0e, E0d, b1e, b1d, wcol0,
      h0p, h1p, xh, xf, y0v,
      encWih0, decWih0, projW, projB,
      out, cntp);
}